// Round 2
// baseline (411.752 us; speedup 1.0000x reference)
//
#include <hip/hip_runtime.h>

#define T_ 16
#define N_ 128
#define F_ 128

__device__ __forceinline__ float fast_tanh(float x) {
    float e = __expf(2.0f * x);
    return 1.0f - __fdividef(2.0f, e + 1.0f);
}

__device__ __forceinline__ float lrelu(float v) {
    return v >= 0.0f ? v : 0.01f * v;
}

// ---------------- prep: transpose node_w (both layers) + zero BN accumulators ----------------
__global__ void prep_k(const float* __restrict__ W, float* __restrict__ WT,
                       float* __restrict__ bn) {
    int l = blockIdx.y;
    int idx = blockIdx.x * 256 + threadIdx.x;   // 0..16383
    int g = idx >> 7, f = idx & 127;
    WT[l * 16384 + f * 128 + g] = W[l * 16384 + idx];
    if (blockIdx.x == 0) bn[l * 256 + threadIdx.x] = 0.0f;  // [l][2][128]
}

// ---------------- fused edge update + aggregate + node update, layer 0 ----------------
// grid 2048 (= t*128+i), block 128. Phase1: edge tanh + j-sum. Phase2: h -> y = W h, BN atomics.
__global__ __launch_bounds__(128) void edgenode_l0(const float* __restrict__ x0,
                                                   const float* __restrict__ E,
                                                   const float* __restrict__ ew,
                                                   const float* __restrict__ eb,
                                                   const float* __restrict__ cw,
                                                   const float* __restrict__ WT,
                                                   float* __restrict__ bn,
                                                   float* __restrict__ ybuf) {
    int ti = blockIdx.x;
    int t = ti >> 7, i = ti & 127;
    int tid = threadIdx.x;
    int jl = tid >> 5, fg = tid & 31;
    float w0 = ew[0], w1 = ew[1], w2 = ew[2], b = eb[0];
    float c0 = cw[0], c1 = cw[1];
    const float4* xt = (const float4*)(x0 + (size_t)t * 16384);
    const float4* Ei = (const float4*)(E + (size_t)ti * 16384);
    float4 xi = xt[i * 32 + fg];
    float ax = 0.0f, ay = 0.0f, az = 0.0f, aw = 0.0f;
    #pragma unroll 8
    for (int jb = 0; jb < 128; jb += 4) {
        int j = jb + jl;
        float4 xj = xt[j * 32 + fg];
        float4 ev = Ei[j * 32 + fg];
        if (j != i) {
            ax += fast_tanh(fmaf(w0, xi.x, fmaf(w1, xi.x - xj.x, fmaf(w2, ev.x, b))));
            ay += fast_tanh(fmaf(w0, xi.y, fmaf(w1, xi.y - xj.y, fmaf(w2, ev.y, b))));
            az += fast_tanh(fmaf(w0, xi.z, fmaf(w1, xi.z - xj.z, fmaf(w2, ev.z, b))));
            aw += fast_tanh(fmaf(w0, xi.w, fmaf(w1, xi.w - xj.w, fmaf(w2, ev.w, b))));
        }
    }
    __shared__ float4 red[128];
    __shared__ float hs[128];
    red[tid] = make_float4(ax, ay, az, aw);
    __syncthreads();
    if (tid < 32) {
        float4 a = red[tid], b4 = red[tid + 32], c = red[tid + 64], d = red[tid + 96];
        float4 h;
        h.x = lrelu(fmaf(c0, xi.x, c1 * (a.x + b4.x + c.x + d.x)));
        h.y = lrelu(fmaf(c0, xi.y, c1 * (a.y + b4.y + c.y + d.y)));
        h.z = lrelu(fmaf(c0, xi.z, c1 * (a.z + b4.z + c.z + d.z)));
        h.w = lrelu(fmaf(c0, xi.w, c1 * (a.w + b4.w + c.w + d.w)));
        *(float4*)&hs[tid * 4] = h;   // fg == tid for tid<32, so xi covers feats 4*tid..
    }
    __syncthreads();
    int g = tid;
    float acc = 0.0f;
    #pragma unroll 4
    for (int f = 0; f < 128; f += 4) {
        float4 h4 = *(float4*)&hs[f];   // wave-uniform broadcast
        acc = fmaf(h4.x, WT[f * 128 + g],
              fmaf(h4.y, WT[(f + 1) * 128 + g],
              fmaf(h4.z, WT[(f + 2) * 128 + g],
              fmaf(h4.w, WT[(f + 3) * 128 + g], acc))));
    }
    ybuf[(size_t)ti * 128 + g] = acc;
    atomicAdd(&bn[g], acc);
    atomicAdd(&bn[128 + g], acc * acc);
}

// ---------------- same, layer 1: recompute e0 from original E on the fly ----------------
__global__ __launch_bounds__(128) void edgenode_l1(const float* __restrict__ x0,
                                                   const float* __restrict__ x1,
                                                   const float* __restrict__ E,
                                                   const float* __restrict__ ew,
                                                   const float* __restrict__ eb,
                                                   const float* __restrict__ cw,
                                                   const float* __restrict__ WT,
                                                   float* __restrict__ bn,
                                                   float* __restrict__ ybuf) {
    int ti = blockIdx.x;
    int t = ti >> 7, i = ti & 127;
    int tid = threadIdx.x;
    int jl = tid >> 5, fg = tid & 31;
    float w00 = ew[0], w01 = ew[1], w02 = ew[2], b0 = eb[0];
    float w10 = ew[3], w11 = ew[4], w12 = ew[5], b1 = eb[1];
    float c0 = cw[2], c1 = cw[3];
    const float4* xt0 = (const float4*)(x0 + (size_t)t * 16384);
    const float4* xt1 = (const float4*)(x1 + (size_t)t * 16384);
    const float4* Ei = (const float4*)(E + (size_t)ti * 16384);
    float4 xi0 = xt0[i * 32 + fg];
    float4 xi1 = xt1[i * 32 + fg];
    float ax = 0.0f, ay = 0.0f, az = 0.0f, aw = 0.0f;
    #pragma unroll 4
    for (int jb = 0; jb < 128; jb += 4) {
        int j = jb + jl;
        float4 xj0 = xt0[j * 32 + fg];
        float4 xj1 = xt1[j * 32 + fg];
        float4 ev = Ei[j * 32 + fg];
        if (j != i) {
            float e0x = fast_tanh(fmaf(w00, xi0.x, fmaf(w01, xi0.x - xj0.x, fmaf(w02, ev.x, b0))));
            float e0y = fast_tanh(fmaf(w00, xi0.y, fmaf(w01, xi0.y - xj0.y, fmaf(w02, ev.y, b0))));
            float e0z = fast_tanh(fmaf(w00, xi0.z, fmaf(w01, xi0.z - xj0.z, fmaf(w02, ev.z, b0))));
            float e0w = fast_tanh(fmaf(w00, xi0.w, fmaf(w01, xi0.w - xj0.w, fmaf(w02, ev.w, b0))));
            ax += fast_tanh(fmaf(w10, xi1.x, fmaf(w11, xi1.x - xj1.x, fmaf(w12, e0x, b1))));
            ay += fast_tanh(fmaf(w10, xi1.y, fmaf(w11, xi1.y - xj1.y, fmaf(w12, e0y, b1))));
            az += fast_tanh(fmaf(w10, xi1.z, fmaf(w11, xi1.z - xj1.z, fmaf(w12, e0z, b1))));
            aw += fast_tanh(fmaf(w10, xi1.w, fmaf(w11, xi1.w - xj1.w, fmaf(w12, e0w, b1))));
        }
    }
    __shared__ float4 red[128];
    __shared__ float hs[128];
    red[tid] = make_float4(ax, ay, az, aw);
    __syncthreads();
    if (tid < 32) {
        float4 a = red[tid], b4 = red[tid + 32], c = red[tid + 64], d = red[tid + 96];
        float4 h;
        h.x = lrelu(fmaf(c0, xi1.x, c1 * (a.x + b4.x + c.x + d.x)));
        h.y = lrelu(fmaf(c0, xi1.y, c1 * (a.y + b4.y + c.y + d.y)));
        h.z = lrelu(fmaf(c0, xi1.z, c1 * (a.z + b4.z + c.z + d.z)));
        h.w = lrelu(fmaf(c0, xi1.w, c1 * (a.w + b4.w + c.w + d.w)));
        *(float4*)&hs[tid * 4] = h;
    }
    __syncthreads();
    int g = tid;
    float acc = 0.0f;
    #pragma unroll 4
    for (int f = 0; f < 128; f += 4) {
        float4 h4 = *(float4*)&hs[f];
        acc = fmaf(h4.x, WT[f * 128 + g],
              fmaf(h4.y, WT[(f + 1) * 128 + g],
              fmaf(h4.z, WT[(f + 2) * 128 + g],
              fmaf(h4.w, WT[(f + 3) * 128 + g], acc))));
    }
    ybuf[(size_t)ti * 128 + g] = acc;
    atomicAdd(&bn[g], acc);
    atomicAdd(&bn[128 + g], acc * acc);
}

// ---------------- fused BN(+lrelu) + sim_cal; ch==0 blocks also emit x_next ----------------
// grid (T, 8), block 128. bnsum==nullptr -> plain sim_cal on y.
__global__ __launch_bounds__(128) void sim_bn_k(const float* __restrict__ y,
                                                const float* __restrict__ bnsum,
                                                const float* __restrict__ gamma,
                                                const float* __restrict__ beta,
                                                float* __restrict__ out,
                                                float* __restrict__ xout) {
    __shared__ float Xs[128][132];
    __shared__ float nrm[128];
    int t = blockIdx.x, ch = blockIdx.y;
    int m = threadIdx.x;
    const float* yt = y + (size_t)t * (N_ * F_);
    int fg = (m & 31) * 4, ko = m >> 5;

    bool dobn = (bnsum != nullptr);
    float4 mu4 = make_float4(0, 0, 0, 0), inv4 = mu4, ga4 = mu4, be4 = mu4;
    if (dobn) {
        float4 s = *(const float4*)&bnsum[fg];
        float4 q = *(const float4*)&bnsum[128 + fg];
        ga4 = *(const float4*)&gamma[fg];
        be4 = *(const float4*)&beta[fg];
        const float r = 1.0f / 2048.0f;
        mu4 = make_float4(s.x * r, s.y * r, s.z * r, s.w * r);
        inv4.x = rsqrtf(q.x * r - mu4.x * mu4.x + 1e-5f);
        inv4.y = rsqrtf(q.y * r - mu4.y * mu4.y + 1e-5f);
        inv4.z = rsqrtf(q.z * r - mu4.z * mu4.z + 1e-5f);
        inv4.w = rsqrtf(q.w * r - mu4.w * mu4.w + 1e-5f);
    }
    bool wx = (xout != nullptr) && (ch == 0);

    for (int kb = 0; kb < 128; kb += 4) {
        int k = kb + ko;
        float4 v = *(const float4*)(yt + k * 128 + fg);
        if (dobn) {
            v.x = lrelu((v.x - mu4.x) * inv4.x * ga4.x + be4.x);
            v.y = lrelu((v.y - mu4.y) * inv4.y * ga4.y + be4.y);
            v.z = lrelu((v.z - mu4.z) * inv4.z * ga4.z + be4.z);
            v.w = lrelu((v.w - mu4.w) * inv4.w * ga4.w + be4.w);
        }
        *(float4*)&Xs[k][fg] = v;
        if (wx) *(float4*)(xout + (size_t)t * 16384 + k * 128 + fg) = v;
    }
    __syncthreads();

    float s = 0.0f;
    #pragma unroll 8
    for (int f = 0; f < 128; f += 4) {
        float4 v = *(float4*)&Xs[m][f];
        s += v.x * v.x + v.y * v.y + v.z * v.z + v.w * v.w;
    }
    nrm[m] = sqrtf(s);
    __syncthreads();

    float acc[16];
    #pragma unroll
    for (int r = 0; r < 16; ++r) acc[r] = 0.0f;

    for (int fc = 0; fc < 128; fc += 32) {
        float xm[32];
        #pragma unroll
        for (int f = 0; f < 32; f += 4) {
            float4 v = *(float4*)&Xs[m][fc + f];
            xm[f] = v.x; xm[f + 1] = v.y; xm[f + 2] = v.z; xm[f + 3] = v.w;
        }
        #pragma unroll
        for (int r = 0; r < 16; ++r) {
            int n = ch * 16 + r;
            #pragma unroll
            for (int f = 0; f < 32; f += 4) {
                float4 v = *(float4*)&Xs[n][fc + f];
                acc[r] = fmaf(xm[f], v.x,
                         fmaf(xm[f + 1], v.y,
                         fmaf(xm[f + 2], v.z,
                         fmaf(xm[f + 3], v.w, acc[r]))));
            }
        }
    }

    float nm = nrm[m];
    size_t ob = (size_t)t * 2 * 16384;
    #pragma unroll
    for (int r = 0; r < 16; ++r) {
        int n = ch * 16 + r;
        float denom = nrm[n] * nm + 1e-6f;
        float sim = __fdividef(acc[r], denom);
        float s0 = fminf(fmaxf(sim, 0.0f), 1.0f);
        float s1 = fminf(fmaxf(1.0f - sim, 0.0f), 1.0f);
        out[ob + (size_t)n * 128 + m] = s0;
        out[ob + 16384 + (size_t)n * 128 + m] = s1;
    }
}

extern "C" void kernel_launch(void* const* d_in, const int* in_sizes, int n_in,
                              void* d_out, int out_size, void* d_ws, size_t ws_size,
                              hipStream_t stream) {
    const float* x0    = (const float*)d_in[0];
    const float* E     = (const float*)d_in[1];
    const float* ew    = (const float*)d_in[2];
    const float* eb    = (const float*)d_in[3];
    const float* cw    = (const float*)d_in[4];
    const float* nw    = (const float*)d_in[5];
    const float* gamma = (const float*)d_in[6];
    const float* beta  = (const float*)d_in[7];
    float* out = (float*)d_out;

    float* ws   = (float*)d_ws;
    float* x1   = ws;                // 262144
    float* ybuf = ws + 262144;       // 262144
    float* bn   = ws + 524288;       // 512  ([l][sum|sumsq][128])
    float* WT   = ws + 524800;       // 32768

    prep_k<<<dim3(64, 2), 256, 0, stream>>>(nw, WT, bn);

    // out[0] = sim_cal(x0)
    sim_bn_k<<<dim3(16, 8), 128, 0, stream>>>(x0, nullptr, nullptr, nullptr, out, nullptr);

    // layer 0
    edgenode_l0<<<2048, 128, 0, stream>>>(x0, E, ew, eb, cw, WT, bn, ybuf);
    sim_bn_k<<<dim3(16, 8), 128, 0, stream>>>(ybuf, bn, gamma, beta, out + 524288, x1);

    // layer 1
    edgenode_l1<<<2048, 128, 0, stream>>>(x0, x1, E, ew, eb, cw, WT + 16384, bn + 256, ybuf);
    sim_bn_k<<<dim3(16, 8), 128, 0, stream>>>(ybuf, bn + 256, gamma + 128, beta + 128,
                                              out + 1048576, nullptr);
}

// Round 3
// 381.950 us; speedup vs baseline: 1.0780x; 1.0780x over previous
//
#include <hip/hip_runtime.h>

#define T_ 16
#define N_ 128
#define F_ 128

__device__ __forceinline__ float fast_tanh(float x) {
    float e = __expf(2.0f * x);
    return 1.0f - __fdividef(2.0f, e + 1.0f);
}

__device__ __forceinline__ float lrelu(float v) {
    return v >= 0.0f ? v : 0.01f * v;
}

// ---------------- prep: transpose node_w (both layers) + zero BN accumulators ----------------
__global__ void prep_k(const float* __restrict__ W, float* __restrict__ WT,
                       float* __restrict__ bn) {
    int l = blockIdx.y;
    int idx = blockIdx.x * 256 + threadIdx.x;   // 0..16383
    int g = idx >> 7, f = idx & 127;
    WT[l * 16384 + f * 128 + g] = W[l * 16384 + idx];
    if (blockIdx.x == 0) bn[l * 256 + threadIdx.x] = 0.0f;  // [l][2][128]
}

// ---------------- fused edge update + aggregate + node update, layer 0 ----------------
// grid 2048 (= t*128+i), block 256 (jl 0..7 x fg 0..31). Branchless: sum all j, subtract j==i term.
__global__ __launch_bounds__(256, 8) void edgenode_l0(const float* __restrict__ x0,
                                                      const float* __restrict__ E,
                                                      const float* __restrict__ ew,
                                                      const float* __restrict__ eb,
                                                      const float* __restrict__ cw,
                                                      const float* __restrict__ WT,
                                                      float* __restrict__ bn,
                                                      float* __restrict__ ybuf) {
    int ti = blockIdx.x;
    int t = ti >> 7, i = ti & 127;
    int tid = threadIdx.x;
    int jl = tid >> 5, fg = tid & 31;
    float w0 = ew[0], w1 = ew[1], w2 = ew[2], b = eb[0];
    float c0 = cw[0], c1 = cw[1];
    const float4* xt = (const float4*)(x0 + (size_t)t * 16384);
    const float4* Ei = (const float4*)(E + (size_t)ti * 16384);
    float4 xi = xt[i * 32 + fg];
    float ax = 0.0f, ay = 0.0f, az = 0.0f, aw = 0.0f;
    #pragma unroll 4
    for (int jb = 0; jb < 128; jb += 8) {
        int j = jb + jl;
        float4 xj = xt[j * 32 + fg];
        float4 ev = Ei[j * 32 + fg];
        ax += fast_tanh(fmaf(w0, xi.x, fmaf(w1, xi.x - xj.x, fmaf(w2, ev.x, b))));
        ay += fast_tanh(fmaf(w0, xi.y, fmaf(w1, xi.y - xj.y, fmaf(w2, ev.y, b))));
        az += fast_tanh(fmaf(w0, xi.z, fmaf(w1, xi.z - xj.z, fmaf(w2, ev.z, b))));
        aw += fast_tanh(fmaf(w0, xi.w, fmaf(w1, xi.w - xj.w, fmaf(w2, ev.w, b))));
    }
    __shared__ float4 red[256];
    __shared__ float hs[128];
    __shared__ float part[256];
    red[tid] = make_float4(ax, ay, az, aw);
    __syncthreads();
    if (tid < 32) {
        float4 s = red[tid];
        #pragma unroll
        for (int k = 1; k < 8; ++k) {
            float4 v = red[tid + 32 * k];
            s.x += v.x; s.y += v.y; s.z += v.z; s.w += v.w;
        }
        // subtract the j==i contribution (loop computed it with diff==0, exactly)
        float4 Eii = Ei[i * 32 + tid];
        s.x -= fast_tanh(fmaf(w0, xi.x, fmaf(w1, 0.0f, fmaf(w2, Eii.x, b))));
        s.y -= fast_tanh(fmaf(w0, xi.y, fmaf(w1, 0.0f, fmaf(w2, Eii.y, b))));
        s.z -= fast_tanh(fmaf(w0, xi.z, fmaf(w1, 0.0f, fmaf(w2, Eii.z, b))));
        s.w -= fast_tanh(fmaf(w0, xi.w, fmaf(w1, 0.0f, fmaf(w2, Eii.w, b))));
        float4 h;
        h.x = lrelu(fmaf(c0, xi.x, c1 * s.x));
        h.y = lrelu(fmaf(c0, xi.y, c1 * s.y));
        h.z = lrelu(fmaf(c0, xi.z, c1 * s.z));
        h.w = lrelu(fmaf(c0, xi.w, c1 * s.w));
        *(float4*)&hs[tid * 4] = h;    // fg==tid for tid<32
    }
    __syncthreads();
    // phase 2: y = W h. 256 threads: g = tid&127 output, half splits the f-sum.
    int g = tid & 127, half = tid >> 7;
    const float* Wh = WT + half * 64 * 128;
    const float* hh = hs + half * 64;
    float acc = 0.0f;
    #pragma unroll 4
    for (int f = 0; f < 64; f += 4) {
        float4 h4 = *(const float4*)&hh[f];
        acc = fmaf(h4.x, Wh[f * 128 + g],
              fmaf(h4.y, Wh[(f + 1) * 128 + g],
              fmaf(h4.z, Wh[(f + 2) * 128 + g],
              fmaf(h4.w, Wh[(f + 3) * 128 + g], acc))));
    }
    part[tid] = acc;
    __syncthreads();
    if (tid < 128) {
        float y = part[tid] + part[tid + 128];
        ybuf[(size_t)ti * 128 + tid] = y;
        atomicAdd(&bn[tid], y);
        atomicAdd(&bn[128 + tid], y * y);
    }
}

// ---------------- same, layer 1: recompute e0 from original E on the fly ----------------
__global__ __launch_bounds__(256, 8) void edgenode_l1(const float* __restrict__ x0,
                                                      const float* __restrict__ x1,
                                                      const float* __restrict__ E,
                                                      const float* __restrict__ ew,
                                                      const float* __restrict__ eb,
                                                      const float* __restrict__ cw,
                                                      const float* __restrict__ WT,
                                                      float* __restrict__ bn,
                                                      float* __restrict__ ybuf) {
    int ti = blockIdx.x;
    int t = ti >> 7, i = ti & 127;
    int tid = threadIdx.x;
    int jl = tid >> 5, fg = tid & 31;
    float w00 = ew[0], w01 = ew[1], w02 = ew[2], b0 = eb[0];
    float w10 = ew[3], w11 = ew[4], w12 = ew[5], b1 = eb[1];
    float c0 = cw[2], c1 = cw[3];
    const float4* xt0 = (const float4*)(x0 + (size_t)t * 16384);
    const float4* xt1 = (const float4*)(x1 + (size_t)t * 16384);
    const float4* Ei = (const float4*)(E + (size_t)ti * 16384);
    float4 xi0 = xt0[i * 32 + fg];
    float4 xi1 = xt1[i * 32 + fg];
    float ax = 0.0f, ay = 0.0f, az = 0.0f, aw = 0.0f;
    #pragma unroll 2
    for (int jb = 0; jb < 128; jb += 8) {
        int j = jb + jl;
        float4 xj0 = xt0[j * 32 + fg];
        float4 xj1 = xt1[j * 32 + fg];
        float4 ev = Ei[j * 32 + fg];
        float e0x = fast_tanh(fmaf(w00, xi0.x, fmaf(w01, xi0.x - xj0.x, fmaf(w02, ev.x, b0))));
        float e0y = fast_tanh(fmaf(w00, xi0.y, fmaf(w01, xi0.y - xj0.y, fmaf(w02, ev.y, b0))));
        float e0z = fast_tanh(fmaf(w00, xi0.z, fmaf(w01, xi0.z - xj0.z, fmaf(w02, ev.z, b0))));
        float e0w = fast_tanh(fmaf(w00, xi0.w, fmaf(w01, xi0.w - xj0.w, fmaf(w02, ev.w, b0))));
        ax += fast_tanh(fmaf(w10, xi1.x, fmaf(w11, xi1.x - xj1.x, fmaf(w12, e0x, b1))));
        ay += fast_tanh(fmaf(w10, xi1.y, fmaf(w11, xi1.y - xj1.y, fmaf(w12, e0y, b1))));
        az += fast_tanh(fmaf(w10, xi1.z, fmaf(w11, xi1.z - xj1.z, fmaf(w12, e0z, b1))));
        aw += fast_tanh(fmaf(w10, xi1.w, fmaf(w11, xi1.w - xj1.w, fmaf(w12, e0w, b1))));
    }
    __shared__ float4 red[256];
    __shared__ float hs[128];
    __shared__ float part[256];
    red[tid] = make_float4(ax, ay, az, aw);
    __syncthreads();
    if (tid < 32) {
        float4 s = red[tid];
        #pragma unroll
        for (int k = 1; k < 8; ++k) {
            float4 v = red[tid + 32 * k];
            s.x += v.x; s.y += v.y; s.z += v.z; s.w += v.w;
        }
        float4 Eii = Ei[i * 32 + tid];
        float e0x = fast_tanh(fmaf(w00, xi0.x, fmaf(w01, 0.0f, fmaf(w02, Eii.x, b0))));
        float e0y = fast_tanh(fmaf(w00, xi0.y, fmaf(w01, 0.0f, fmaf(w02, Eii.y, b0))));
        float e0z = fast_tanh(fmaf(w00, xi0.z, fmaf(w01, 0.0f, fmaf(w02, Eii.z, b0))));
        float e0w = fast_tanh(fmaf(w00, xi0.w, fmaf(w01, 0.0f, fmaf(w02, Eii.w, b0))));
        s.x -= fast_tanh(fmaf(w10, xi1.x, fmaf(w11, 0.0f, fmaf(w12, e0x, b1))));
        s.y -= fast_tanh(fmaf(w10, xi1.y, fmaf(w11, 0.0f, fmaf(w12, e0y, b1))));
        s.z -= fast_tanh(fmaf(w10, xi1.z, fmaf(w11, 0.0f, fmaf(w12, e0z, b1))));
        s.w -= fast_tanh(fmaf(w10, xi1.w, fmaf(w11, 0.0f, fmaf(w12, e0w, b1))));
        float4 h;
        h.x = lrelu(fmaf(c0, xi1.x, c1 * s.x));
        h.y = lrelu(fmaf(c0, xi1.y, c1 * s.y));
        h.z = lrelu(fmaf(c0, xi1.z, c1 * s.z));
        h.w = lrelu(fmaf(c0, xi1.w, c1 * s.w));
        *(float4*)&hs[tid * 4] = h;
    }
    __syncthreads();
    int g = tid & 127, half = tid >> 7;
    const float* Wh = WT + half * 64 * 128;
    const float* hh = hs + half * 64;
    float acc = 0.0f;
    #pragma unroll 4
    for (int f = 0; f < 64; f += 4) {
        float4 h4 = *(const float4*)&hh[f];
        acc = fmaf(h4.x, Wh[f * 128 + g],
              fmaf(h4.y, Wh[(f + 1) * 128 + g],
              fmaf(h4.z, Wh[(f + 2) * 128 + g],
              fmaf(h4.w, Wh[(f + 3) * 128 + g], acc))));
    }
    part[tid] = acc;
    __syncthreads();
    if (tid < 128) {
        float y = part[tid] + part[tid + 128];
        ybuf[(size_t)ti * 128 + tid] = y;
        atomicAdd(&bn[tid], y);
        atomicAdd(&bn[128 + tid], y * y);
    }
}

// ---------------- fused BN(+lrelu) + sim_cal; ch==0 blocks also emit x_next ----------------
// grid (T, 16), block 128: each block computes 8 n-rows x 128 m-cols.
#define NR 8
__global__ __launch_bounds__(128) void sim_bn_k(const float* __restrict__ y,
                                                const float* __restrict__ bnsum,
                                                const float* __restrict__ gamma,
                                                const float* __restrict__ beta,
                                                float* __restrict__ out,
                                                float* __restrict__ xout) {
    __shared__ float Xs[128][132];
    __shared__ float nrm[128];
    int t = blockIdx.x, ch = blockIdx.y;
    int m = threadIdx.x;
    const float* yt = y + (size_t)t * (N_ * F_);
    int fg = (m & 31) * 4, ko = m >> 5;

    bool dobn = (bnsum != nullptr);
    float4 mu4 = make_float4(0, 0, 0, 0), inv4 = mu4, ga4 = mu4, be4 = mu4;
    if (dobn) {
        float4 s = *(const float4*)&bnsum[fg];
        float4 q = *(const float4*)&bnsum[128 + fg];
        ga4 = *(const float4*)&gamma[fg];
        be4 = *(const float4*)&beta[fg];
        const float r = 1.0f / 2048.0f;
        mu4 = make_float4(s.x * r, s.y * r, s.z * r, s.w * r);
        inv4.x = rsqrtf(q.x * r - mu4.x * mu4.x + 1e-5f);
        inv4.y = rsqrtf(q.y * r - mu4.y * mu4.y + 1e-5f);
        inv4.z = rsqrtf(q.z * r - mu4.z * mu4.z + 1e-5f);
        inv4.w = rsqrtf(q.w * r - mu4.w * mu4.w + 1e-5f);
    }
    bool wx = (xout != nullptr) && (ch == 0);

    for (int kb = 0; kb < 128; kb += 4) {
        int k = kb + ko;
        float4 v = *(const float4*)(yt + k * 128 + fg);
        if (dobn) {
            v.x = lrelu((v.x - mu4.x) * inv4.x * ga4.x + be4.x);
            v.y = lrelu((v.y - mu4.y) * inv4.y * ga4.y + be4.y);
            v.z = lrelu((v.z - mu4.z) * inv4.z * ga4.z + be4.z);
            v.w = lrelu((v.w - mu4.w) * inv4.w * ga4.w + be4.w);
        }
        *(float4*)&Xs[k][fg] = v;
        if (wx) *(float4*)(xout + (size_t)t * 16384 + k * 128 + fg) = v;
    }
    __syncthreads();

    float s = 0.0f;
    #pragma unroll 8
    for (int f = 0; f < 128; f += 4) {
        float4 v = *(float4*)&Xs[m][f];
        s += v.x * v.x + v.y * v.y + v.z * v.z + v.w * v.w;
    }
    nrm[m] = sqrtf(s);
    __syncthreads();

    float acc[NR];
    #pragma unroll
    for (int r = 0; r < NR; ++r) acc[r] = 0.0f;

    for (int fc = 0; fc < 128; fc += 32) {
        float xm[32];
        #pragma unroll
        for (int f = 0; f < 32; f += 4) {
            float4 v = *(float4*)&Xs[m][fc + f];
            xm[f] = v.x; xm[f + 1] = v.y; xm[f + 2] = v.z; xm[f + 3] = v.w;
        }
        #pragma unroll
        for (int r = 0; r < NR; ++r) {
            int n = ch * NR + r;
            #pragma unroll
            for (int f = 0; f < 32; f += 4) {
                float4 v = *(float4*)&Xs[n][fc + f];
                acc[r] = fmaf(xm[f], v.x,
                         fmaf(xm[f + 1], v.y,
                         fmaf(xm[f + 2], v.z,
                         fmaf(xm[f + 3], v.w, acc[r]))));
            }
        }
    }

    float nm = nrm[m];
    size_t ob = (size_t)t * 2 * 16384;
    #pragma unroll
    for (int r = 0; r < NR; ++r) {
        int n = ch * NR + r;
        float denom = nrm[n] * nm + 1e-6f;
        float sim = __fdividef(acc[r], denom);
        float s0 = fminf(fmaxf(sim, 0.0f), 1.0f);
        float s1 = fminf(fmaxf(1.0f - sim, 0.0f), 1.0f);
        out[ob + (size_t)n * 128 + m] = s0;
        out[ob + 16384 + (size_t)n * 128 + m] = s1;
    }
}

extern "C" void kernel_launch(void* const* d_in, const int* in_sizes, int n_in,
                              void* d_out, int out_size, void* d_ws, size_t ws_size,
                              hipStream_t stream) {
    const float* x0    = (const float*)d_in[0];
    const float* E     = (const float*)d_in[1];
    const float* ew    = (const float*)d_in[2];
    const float* eb    = (const float*)d_in[3];
    const float* cw    = (const float*)d_in[4];
    const float* nw    = (const float*)d_in[5];
    const float* gamma = (const float*)d_in[6];
    const float* beta  = (const float*)d_in[7];
    float* out = (float*)d_out;

    float* ws   = (float*)d_ws;
    float* x1   = ws;                // 262144
    float* ybuf = ws + 262144;       // 262144
    float* bn   = ws + 524288;       // 512  ([l][sum|sumsq][128])
    float* WT   = ws + 524800;       // 32768

    prep_k<<<dim3(64, 2), 256, 0, stream>>>(nw, WT, bn);

    // out[0] = sim_cal(x0)
    sim_bn_k<<<dim3(16, 16), 128, 0, stream>>>(x0, nullptr, nullptr, nullptr, out, nullptr);

    // layer 0
    edgenode_l0<<<2048, 256, 0, stream>>>(x0, E, ew, eb, cw, WT, bn, ybuf);
    sim_bn_k<<<dim3(16, 16), 128, 0, stream>>>(ybuf, bn, gamma, beta, out + 524288, x1);

    // layer 1
    edgenode_l1<<<2048, 256, 0, stream>>>(x0, x1, E, ew, eb, cw, WT + 16384, bn + 256, ybuf);
    sim_bn_k<<<dim3(16, 16), 128, 0, stream>>>(ybuf, bn + 256, gamma + 128, beta + 128,
                                               out + 1048576, nullptr);
}

// Round 4
// 358.711 us; speedup vs baseline: 1.1479x; 1.0648x over previous
//
#include <hip/hip_runtime.h>

#define T_ 16
#define N_ 128
#define F_ 128

__device__ __forceinline__ float fast_tanh(float x) {
    float e = __expf(2.0f * x);
    return 1.0f - __fdividef(2.0f, e + 1.0f);
}

__device__ __forceinline__ float lrelu(float v) {
    return v >= 0.0f ? v : 0.01f * v;
}

// ---------------- prep: transpose node_w (both layers) + zero BN accumulators ----------------
__global__ void prep_k(const float* __restrict__ W, float* __restrict__ WT,
                       float* __restrict__ bn) {
    int l = blockIdx.y;
    int idx = blockIdx.x * 256 + threadIdx.x;   // 0..16383
    int g = idx >> 7, f = idx & 127;
    WT[l * 16384 + f * 128 + g] = W[l * 16384 + idx];
    if (blockIdx.x == 0) bn[l * 256 + threadIdx.x] = 0.0f;  // [l][2][128]
}

// ---------------- fused edge update + aggregate + node update, layer 0 ----------------
// grid 2048 (= t*128+i), block 256 (jl 0..7 x fg 0..31).
// Explicit register double-buffer (batch=4 j-steps) to keep 8 loads in flight per wave.
__global__ __launch_bounds__(256) void edgenode_l0(const float* __restrict__ x0,
                                                   const float* __restrict__ E,
                                                   const float* __restrict__ ew,
                                                   const float* __restrict__ eb,
                                                   const float* __restrict__ cw,
                                                   const float* __restrict__ WT,
                                                   float* __restrict__ bn,
                                                   float* __restrict__ ybuf) {
    int ti = blockIdx.x;
    int t = ti >> 7, i = ti & 127;
    int tid = threadIdx.x;
    int jl = tid >> 5, fg = tid & 31;
    float w0 = ew[0], w1 = ew[1], w2 = ew[2], b = eb[0];
    float c0 = cw[0], c1 = cw[1];
    const float4* xt = (const float4*)(x0 + (size_t)t * 16384);
    const float4* Ei = (const float4*)(E + (size_t)ti * 16384);
    float4 xi = xt[i * 32 + fg];

    float4 xb[2][4], ebf[2][4];
    #pragma unroll
    for (int u = 0; u < 4; ++u) {
        int j = jl + 8 * u;
        xb[0][u]  = xt[j * 32 + fg];
        ebf[0][u] = Ei[j * 32 + fg];
    }
    float ax = 0.0f, ay = 0.0f, az = 0.0f, aw = 0.0f;
    #pragma unroll
    for (int bt = 0; bt < 4; ++bt) {
        int cur = bt & 1, nxt = cur ^ 1;
        if (bt < 3) {
            #pragma unroll
            for (int u = 0; u < 4; ++u) {
                int j = jl + 8 * (4 * (bt + 1) + u);
                xb[nxt][u]  = xt[j * 32 + fg];
                ebf[nxt][u] = Ei[j * 32 + fg];
            }
        }
        #pragma unroll
        for (int u = 0; u < 4; ++u) {
            float4 xj = xb[cur][u], ev = ebf[cur][u];
            ax += fast_tanh(fmaf(w0, xi.x, fmaf(w1, xi.x - xj.x, fmaf(w2, ev.x, b))));
            ay += fast_tanh(fmaf(w0, xi.y, fmaf(w1, xi.y - xj.y, fmaf(w2, ev.y, b))));
            az += fast_tanh(fmaf(w0, xi.z, fmaf(w1, xi.z - xj.z, fmaf(w2, ev.z, b))));
            aw += fast_tanh(fmaf(w0, xi.w, fmaf(w1, xi.w - xj.w, fmaf(w2, ev.w, b))));
        }
    }

    __shared__ float4 red[256];
    __shared__ float hs[128];
    __shared__ float part[256];
    red[tid] = make_float4(ax, ay, az, aw);
    __syncthreads();
    if (tid < 32) {
        float4 s = red[tid];
        #pragma unroll
        for (int k = 1; k < 8; ++k) {
            float4 v = red[tid + 32 * k];
            s.x += v.x; s.y += v.y; s.z += v.z; s.w += v.w;
        }
        // subtract the j==i contribution (loop computed it with diff==0, bit-identical)
        float4 Eii = Ei[i * 32 + tid];
        s.x -= fast_tanh(fmaf(w0, xi.x, fmaf(w1, 0.0f, fmaf(w2, Eii.x, b))));
        s.y -= fast_tanh(fmaf(w0, xi.y, fmaf(w1, 0.0f, fmaf(w2, Eii.y, b))));
        s.z -= fast_tanh(fmaf(w0, xi.z, fmaf(w1, 0.0f, fmaf(w2, Eii.z, b))));
        s.w -= fast_tanh(fmaf(w0, xi.w, fmaf(w1, 0.0f, fmaf(w2, Eii.w, b))));
        float4 h;
        h.x = lrelu(fmaf(c0, xi.x, c1 * s.x));
        h.y = lrelu(fmaf(c0, xi.y, c1 * s.y));
        h.z = lrelu(fmaf(c0, xi.z, c1 * s.z));
        h.w = lrelu(fmaf(c0, xi.w, c1 * s.w));
        *(float4*)&hs[tid * 4] = h;    // fg==tid for tid<32
    }
    __syncthreads();
    // phase 2: y = W h. 256 threads: g = tid&127 output, half splits the f-sum.
    int g = tid & 127, half = tid >> 7;
    const float* Wh = WT + half * 64 * 128;
    const float* hh = hs + half * 64;
    float acc = 0.0f;
    #pragma unroll 4
    for (int f = 0; f < 64; f += 4) {
        float4 h4 = *(const float4*)&hh[f];
        acc = fmaf(h4.x, Wh[f * 128 + g],
              fmaf(h4.y, Wh[(f + 1) * 128 + g],
              fmaf(h4.z, Wh[(f + 2) * 128 + g],
              fmaf(h4.w, Wh[(f + 3) * 128 + g], acc))));
    }
    part[tid] = acc;
    __syncthreads();
    if (tid < 128) {
        float y = part[tid] + part[tid + 128];
        ybuf[(size_t)ti * 128 + tid] = y;
        atomicAdd(&bn[tid], y);
        atomicAdd(&bn[128 + tid], y * y);
    }
}

// ---------------- same, layer 1: recompute e0 from original E on the fly ----------------
__global__ __launch_bounds__(256) void edgenode_l1(const float* __restrict__ x0,
                                                   const float* __restrict__ x1,
                                                   const float* __restrict__ E,
                                                   const float* __restrict__ ew,
                                                   const float* __restrict__ eb,
                                                   const float* __restrict__ cw,
                                                   const float* __restrict__ WT,
                                                   float* __restrict__ bn,
                                                   float* __restrict__ ybuf) {
    int ti = blockIdx.x;
    int t = ti >> 7, i = ti & 127;
    int tid = threadIdx.x;
    int jl = tid >> 5, fg = tid & 31;
    float w00 = ew[0], w01 = ew[1], w02 = ew[2], b0 = eb[0];
    float w10 = ew[3], w11 = ew[4], w12 = ew[5], b1 = eb[1];
    float c0 = cw[2], c1 = cw[3];
    const float4* xt0 = (const float4*)(x0 + (size_t)t * 16384);
    const float4* xt1 = (const float4*)(x1 + (size_t)t * 16384);
    const float4* Ei = (const float4*)(E + (size_t)ti * 16384);
    float4 xi0 = xt0[i * 32 + fg];
    float4 xi1 = xt1[i * 32 + fg];

    float4 x0b[2][4], x1b[2][4], ebf[2][4];
    #pragma unroll
    for (int u = 0; u < 4; ++u) {
        int j = jl + 8 * u;
        x0b[0][u] = xt0[j * 32 + fg];
        x1b[0][u] = xt1[j * 32 + fg];
        ebf[0][u] = Ei[j * 32 + fg];
    }
    float ax = 0.0f, ay = 0.0f, az = 0.0f, aw = 0.0f;
    #pragma unroll
    for (int bt = 0; bt < 4; ++bt) {
        int cur = bt & 1, nxt = cur ^ 1;
        if (bt < 3) {
            #pragma unroll
            for (int u = 0; u < 4; ++u) {
                int j = jl + 8 * (4 * (bt + 1) + u);
                x0b[nxt][u] = xt0[j * 32 + fg];
                x1b[nxt][u] = xt1[j * 32 + fg];
                ebf[nxt][u] = Ei[j * 32 + fg];
            }
        }
        #pragma unroll
        for (int u = 0; u < 4; ++u) {
            float4 xj0 = x0b[cur][u], xj1 = x1b[cur][u], ev = ebf[cur][u];
            float e0x = fast_tanh(fmaf(w00, xi0.x, fmaf(w01, xi0.x - xj0.x, fmaf(w02, ev.x, b0))));
            float e0y = fast_tanh(fmaf(w00, xi0.y, fmaf(w01, xi0.y - xj0.y, fmaf(w02, ev.y, b0))));
            float e0z = fast_tanh(fmaf(w00, xi0.z, fmaf(w01, xi0.z - xj0.z, fmaf(w02, ev.z, b0))));
            float e0w = fast_tanh(fmaf(w00, xi0.w, fmaf(w01, xi0.w - xj0.w, fmaf(w02, ev.w, b0))));
            ax += fast_tanh(fmaf(w10, xi1.x, fmaf(w11, xi1.x - xj1.x, fmaf(w12, e0x, b1))));
            ay += fast_tanh(fmaf(w10, xi1.y, fmaf(w11, xi1.y - xj1.y, fmaf(w12, e0y, b1))));
            az += fast_tanh(fmaf(w10, xi1.z, fmaf(w11, xi1.z - xj1.z, fmaf(w12, e0z, b1))));
            aw += fast_tanh(fmaf(w10, xi1.w, fmaf(w11, xi1.w - xj1.w, fmaf(w12, e0w, b1))));
        }
    }

    __shared__ float4 red[256];
    __shared__ float hs[128];
    __shared__ float part[256];
    red[tid] = make_float4(ax, ay, az, aw);
    __syncthreads();
    if (tid < 32) {
        float4 s = red[tid];
        #pragma unroll
        for (int k = 1; k < 8; ++k) {
            float4 v = red[tid + 32 * k];
            s.x += v.x; s.y += v.y; s.z += v.z; s.w += v.w;
        }
        float4 Eii = Ei[i * 32 + tid];
        float e0x = fast_tanh(fmaf(w00, xi0.x, fmaf(w01, 0.0f, fmaf(w02, Eii.x, b0))));
        float e0y = fast_tanh(fmaf(w00, xi0.y, fmaf(w01, 0.0f, fmaf(w02, Eii.y, b0))));
        float e0z = fast_tanh(fmaf(w00, xi0.z, fmaf(w01, 0.0f, fmaf(w02, Eii.z, b0))));
        float e0w = fast_tanh(fmaf(w00, xi0.w, fmaf(w01, 0.0f, fmaf(w02, Eii.w, b0))));
        s.x -= fast_tanh(fmaf(w10, xi1.x, fmaf(w11, 0.0f, fmaf(w12, e0x, b1))));
        s.y -= fast_tanh(fmaf(w10, xi1.y, fmaf(w11, 0.0f, fmaf(w12, e0y, b1))));
        s.z -= fast_tanh(fmaf(w10, xi1.z, fmaf(w11, 0.0f, fmaf(w12, e0z, b1))));
        s.w -= fast_tanh(fmaf(w10, xi1.w, fmaf(w11, 0.0f, fmaf(w12, e0w, b1))));
        float4 h;
        h.x = lrelu(fmaf(c0, xi1.x, c1 * s.x));
        h.y = lrelu(fmaf(c0, xi1.y, c1 * s.y));
        h.z = lrelu(fmaf(c0, xi1.z, c1 * s.z));
        h.w = lrelu(fmaf(c0, xi1.w, c1 * s.w));
        *(float4*)&hs[tid * 4] = h;
    }
    __syncthreads();
    int g = tid & 127, half = tid >> 7;
    const float* Wh = WT + half * 64 * 128;
    const float* hh = hs + half * 64;
    float acc = 0.0f;
    #pragma unroll 4
    for (int f = 0; f < 64; f += 4) {
        float4 h4 = *(const float4*)&hh[f];
        acc = fmaf(h4.x, Wh[f * 128 + g],
              fmaf(h4.y, Wh[(f + 1) * 128 + g],
              fmaf(h4.z, Wh[(f + 2) * 128 + g],
              fmaf(h4.w, Wh[(f + 3) * 128 + g], acc))));
    }
    part[tid] = acc;
    __syncthreads();
    if (tid < 128) {
        float y = part[tid] + part[tid + 128];
        ybuf[(size_t)ti * 128 + tid] = y;
        atomicAdd(&bn[tid], y);
        atomicAdd(&bn[128 + tid], y * y);
    }
}

// ---------------- fused BN(+lrelu) + sim_cal; ch==0 blocks also emit x_next ----------------
// grid (T, 16), block 128: each block computes 8 n-rows x 128 m-cols.
#define NR 8
__global__ __launch_bounds__(128) void sim_bn_k(const float* __restrict__ y,
                                                const float* __restrict__ bnsum,
                                                const float* __restrict__ gamma,
                                                const float* __restrict__ beta,
                                                float* __restrict__ out,
                                                float* __restrict__ xout) {
    __shared__ float Xs[128][132];
    __shared__ float nrm[128];
    int t = blockIdx.x, ch = blockIdx.y;
    int m = threadIdx.x;
    const float* yt = y + (size_t)t * (N_ * F_);
    int fg = (m & 31) * 4, ko = m >> 5;

    bool dobn = (bnsum != nullptr);
    float4 mu4 = make_float4(0, 0, 0, 0), inv4 = mu4, ga4 = mu4, be4 = mu4;
    if (dobn) {
        float4 s = *(const float4*)&bnsum[fg];
        float4 q = *(const float4*)&bnsum[128 + fg];
        ga4 = *(const float4*)&gamma[fg];
        be4 = *(const float4*)&beta[fg];
        const float r = 1.0f / 2048.0f;
        mu4 = make_float4(s.x * r, s.y * r, s.z * r, s.w * r);
        inv4.x = rsqrtf(q.x * r - mu4.x * mu4.x + 1e-5f);
        inv4.y = rsqrtf(q.y * r - mu4.y * mu4.y + 1e-5f);
        inv4.z = rsqrtf(q.z * r - mu4.z * mu4.z + 1e-5f);
        inv4.w = rsqrtf(q.w * r - mu4.w * mu4.w + 1e-5f);
    }
    bool wx = (xout != nullptr) && (ch == 0);

    for (int kb = 0; kb < 128; kb += 4) {
        int k = kb + ko;
        float4 v = *(const float4*)(yt + k * 128 + fg);
        if (dobn) {
            v.x = lrelu((v.x - mu4.x) * inv4.x * ga4.x + be4.x);
            v.y = lrelu((v.y - mu4.y) * inv4.y * ga4.y + be4.y);
            v.z = lrelu((v.z - mu4.z) * inv4.z * ga4.z + be4.z);
            v.w = lrelu((v.w - mu4.w) * inv4.w * ga4.w + be4.w);
        }
        *(float4*)&Xs[k][fg] = v;
        if (wx) *(float4*)(xout + (size_t)t * 16384 + k * 128 + fg) = v;
    }
    __syncthreads();

    float s = 0.0f;
    #pragma unroll 8
    for (int f = 0; f < 128; f += 4) {
        float4 v = *(float4*)&Xs[m][f];
        s += v.x * v.x + v.y * v.y + v.z * v.z + v.w * v.w;
    }
    nrm[m] = sqrtf(s);
    __syncthreads();

    float acc[NR];
    #pragma unroll
    for (int r = 0; r < NR; ++r) acc[r] = 0.0f;

    for (int fc = 0; fc < 128; fc += 32) {
        float xm[32];
        #pragma unroll
        for (int f = 0; f < 32; f += 4) {
            float4 v = *(float4*)&Xs[m][fc + f];
            xm[f] = v.x; xm[f + 1] = v.y; xm[f + 2] = v.z; xm[f + 3] = v.w;
        }
        #pragma unroll
        for (int r = 0; r < NR; ++r) {
            int n = ch * NR + r;
            #pragma unroll
            for (int f = 0; f < 32; f += 4) {
                float4 v = *(float4*)&Xs[n][fc + f];
                acc[r] = fmaf(xm[f], v.x,
                         fmaf(xm[f + 1], v.y,
                         fmaf(xm[f + 2], v.z,
                         fmaf(xm[f + 3], v.w, acc[r]))));
            }
        }
    }

    float nm = nrm[m];
    size_t ob = (size_t)t * 2 * 16384;
    #pragma unroll
    for (int r = 0; r < NR; ++r) {
        int n = ch * NR + r;
        float denom = nrm[n] * nm + 1e-6f;
        float sim = __fdividef(acc[r], denom);
        float s0 = fminf(fmaxf(sim, 0.0f), 1.0f);
        float s1 = fminf(fmaxf(1.0f - sim, 0.0f), 1.0f);
        out[ob + (size_t)n * 128 + m] = s0;
        out[ob + 16384 + (size_t)n * 128 + m] = s1;
    }
}

extern "C" void kernel_launch(void* const* d_in, const int* in_sizes, int n_in,
                              void* d_out, int out_size, void* d_ws, size_t ws_size,
                              hipStream_t stream) {
    const float* x0    = (const float*)d_in[0];
    const float* E     = (const float*)d_in[1];
    const float* ew    = (const float*)d_in[2];
    const float* eb    = (const float*)d_in[3];
    const float* cw    = (const float*)d_in[4];
    const float* nw    = (const float*)d_in[5];
    const float* gamma = (const float*)d_in[6];
    const float* beta  = (const float*)d_in[7];
    float* out = (float*)d_out;

    float* ws   = (float*)d_ws;
    float* x1   = ws;                // 262144
    float* ybuf = ws + 262144;       // 262144
    float* bn   = ws + 524288;       // 512  ([l][sum|sumsq][128])
    float* WT   = ws + 524800;       // 32768

    prep_k<<<dim3(64, 2), 256, 0, stream>>>(nw, WT, bn);

    // out[0] = sim_cal(x0)
    sim_bn_k<<<dim3(16, 16), 128, 0, stream>>>(x0, nullptr, nullptr, nullptr, out, nullptr);

    // layer 0
    edgenode_l0<<<2048, 256, 0, stream>>>(x0, E, ew, eb, cw, WT, bn, ybuf);
    sim_bn_k<<<dim3(16, 16), 128, 0, stream>>>(ybuf, bn, gamma, beta, out + 524288, x1);

    // layer 1
    edgenode_l1<<<2048, 256, 0, stream>>>(x0, x1, E, ew, eb, cw, WT + 16384, bn + 256, ybuf);
    sim_bn_k<<<dim3(16, 16), 128, 0, stream>>>(ybuf, bn + 256, gamma + 128, beta + 128,
                                               out + 1048576, nullptr);
}